// Round 4
// baseline (355.305 us; speedup 1.0000x reference)
//
#include <hip/hip_runtime.h>
#include <math.h>

// B=512, T=256, C=384, H=64. One block = one batch, 512 thr = 8 waves (2/SIMD).
// R7 = R6 + restored one-iteration-ahead REGISTER prefetch for W (and x).
// R6 lesson: issuing W loads at loop top with immediate LDS-write consumption
// exposes full vmem latency per chunk before the MFMAs (Mfma 21.4->19.6,
// 131->144us). Steady state now: write regs(chunk cc+1)->LDS (no wait),
// issue loads(chunk cc+2) (drain at end-barrier, overlapped by MFMA),
// 72 MFMAs, 1 barrier. No exposed global latency.
// Numerics unchanged: 3-term bf16 hi/lo split for x,W,q,k; single bf16 P,V.
#define B_ 512
#define T_ 256
#define C_ 384
#define H_ 64

typedef __attribute__((ext_vector_type(8))) short bf16x8;
typedef __attribute__((ext_vector_type(4))) float f32x4;

#define MFMA16(a, b, c) __builtin_amdgcn_mfma_f32_16x16x32_bf16((a), (b), (c), 0, 0, 0)

// ---- LDS map (bytes), total 147456 <= 163840.
// Phase 1: two staging buffers buf[i] @ i*73728, each:
//   XH @+0 (xh[256][40] bf16, 80B rows), XL @+20480,
//   W  @+40960 (32768B: WQH,WQL,WKH,WKL,WVH,WVL @5120 each + 2048 pad).
// Phase 2 (aliased over the buffers, live only after phase 1):
//   KHI@0 khi[256][72], KLO@36864, VT@73728 vT[64][264],
//   QS(s)=107520+s*9216 (4 slots, two shifts), PS(w)=107520+w*2304.
#define BUFSZ    73728u
#define XH_OFF   0u
#define XL_OFF   20480u
#define W_OFF    40960u
#define SM_KHI   0u
#define SM_KLO   36864u
#define SM_VT    73728u
#define SM_QS(s) (107520u + (unsigned)(s)*9216u)
#define SM_PS(w) (107520u + (unsigned)(w)*2304u)
#define SM_BYTES 147456u
#define WCHUNK   32768u   // ws bytes per K-chunk (30720 live + pad)

static __device__ __forceinline__ unsigned short bhi(float x) {
    return (unsigned short)(__float_as_uint(x) >> 16);            // truncate
}
static __device__ __forceinline__ unsigned short blo(float x) {
    float h = __uint_as_float((__float_as_uint(x) >> 16) << 16);
    return (unsigned short)(__float_as_uint(x - h) >> 16);        // residual
}
static __device__ __forceinline__ unsigned short brne(float x) { // round-NE
    unsigned u = __float_as_uint(x);
    return (unsigned short)((u + 0x7FFFu + ((u >> 16) & 1u)) >> 16);
}
static __device__ __forceinline__ unsigned pk_hi(float a, float b) {
    return (unsigned)bhi(a) | ((unsigned)bhi(b) << 16);
}
static __device__ __forceinline__ unsigned pk_lo(float a, float b) {
    return (unsigned)blo(a) | ((unsigned)blo(b) << 16);
}

// ---- Pre-kernel: pack W -> ws in staged-transposed layout, once for all blocks.
// ws[cc*32768 + m*10240 + part*5120 + h*80 + c'*2] = {bhi,blo}(W_m[cc*32+c'][h])
__global__ __launch_bounds__(256)
void wprep(const float* __restrict__ Wq, const float* __restrict__ Wk,
           const float* __restrict__ Wv, unsigned char* __restrict__ ws)
{
    const int cc = blockIdx.x / 3, m = blockIdx.x % 3;
    const float* W = (m == 0) ? Wq : (m == 1) ? Wk : Wv;
    const int tid = threadIdx.x;           // 256 threads
    const int c   = tid >> 3;              // 0..31 (c within chunk)
    const int h0  = (tid & 7) * 8;         // 8 h per thread
    const float* src = W + (size_t)(cc * 32 + c) * H_ + h0;
    unsigned char* dst = ws + (size_t)cc * WCHUNK + (size_t)m * 10240u;
    #pragma unroll
    for (int j = 0; j < 8; ++j) {
        const float v = src[j];
        *(unsigned short*)(dst +         (unsigned)((h0 + j) * 80 + c * 2)) = bhi(v);
        *(unsigned short*)(dst + 5120u + (unsigned)((h0 + j) * 80 + c * 2)) = blo(v);
    }
}

__global__ __launch_bounds__(512, 2)
void head_mfma(const float* __restrict__ x,
               const unsigned char* __restrict__ wpack,
               float* __restrict__ out)
{
    __shared__ __align__(16) unsigned char sm[SM_BYTES];

    const int tid  = threadIdx.x;
    const int b    = blockIdx.x;
    const int w    = tid >> 6;        // wave 0..7
    const int lane = tid & 63;
    const int l15  = lane & 15;
    const int quad = lane >> 4;
    const int rA   = w * 16;          // tile A rows [rA, rA+16)
    const int rB   = 240 - w * 16;    // tile B rows [rB, rB+16)

    // ================= Phase 1: q,k,v projections via MFMA =================
    f32x4 qac[2][4], kac[2][4], vac[2][4];
    #pragma unroll
    for (int mt = 0; mt < 2; ++mt)
        #pragma unroll
        for (int nt = 0; nt < 4; ++nt) {
            f32x4 z = {0.f, 0.f, 0.f, 0.f};
            qac[mt][nt] = z; kac[mt][nt] = z; vac[mt][nt] = z;
        }

    const int xrowi = tid >> 1;           // staged x row 0..255
    const int xhalf = tid & 1;            // which 16-float half of the chunk
    const float* xrow = x + ((size_t)b * T_ + xrowi) * C_ + xhalf * 16;

    float4 xb[4];
    uint4  wt[4];

#define X_PACK(BUF)                                                           \
    {                                                                         \
        _Pragma("unroll")                                                     \
        for (int j = 0; j < 4; ++j) {                                         \
            uint2 hh, ll;                                                     \
            hh.x = pk_hi(xb[j].x, xb[j].y); hh.y = pk_hi(xb[j].z, xb[j].w);   \
            ll.x = pk_lo(xb[j].x, xb[j].y); ll.y = pk_lo(xb[j].z, xb[j].w);   \
            *(uint2*)&sm[(BUF) + XH_OFF + (unsigned)(xrowi*80 + xhalf*32 + j*8)] = hh; \
            *(uint2*)&sm[(BUF) + XL_OFF + (unsigned)(xrowi*80 + xhalf*32 + j*8)] = ll; \
        }                                                                     \
    }
#define W_WRITE(BUF)                                                          \
    {                                                                         \
        _Pragma("unroll")                                                     \
        for (int j = 0; j < 4; ++j)                                           \
            *(uint4*)&sm[(BUF) + W_OFF + (unsigned)(j*512 + tid) * 16u] = wt[j]; \
    }
#define PREFETCH(CC)                                                          \
    {                                                                         \
        const float4* xp = (const float4*)(xrow + (CC) * 32);                 \
        _Pragma("unroll")                                                     \
        for (int j = 0; j < 4; ++j) xb[j] = xp[j];                            \
        const uint4* wsrc = (const uint4*)(wpack + (size_t)(CC) * WCHUNK);    \
        _Pragma("unroll")                                                     \
        for (int j = 0; j < 4; ++j) wt[j] = wsrc[j*512 + tid];                \
    }

    // ---- prologue: load chunk 0, write to buf0, prefetch chunk 1 into regs
    PREFETCH(0)
    X_PACK(0u)
    W_WRITE(0u)
    PREFETCH(1)
    __syncthreads();   // drains chunk-1 loads too (barrier waits vmcnt 0)

    #pragma unroll 1
    for (int cc = 0; cc < 12; ++cc) {
        const unsigned bc = (unsigned)(cc & 1) * BUFSZ;   // compute buffer
        // ---- write chunk cc+1 (already in regs) into spare buffer: no waits
        if (cc < 11) {
            const unsigned bn = BUFSZ - bc;
            X_PACK(bn)
            W_WRITE(bn)
            if (cc < 10) PREFETCH(cc + 2)   // overlaps MFMAs below
        }

        // ---- A fragments for the wave's two 16-row tiles, hi & lo
        bf16x8 ah[2], al[2];
        {
            const unsigned roA = (unsigned)((rA + l15)*80 + quad*16);
            const unsigned roB = (unsigned)((rB + l15)*80 + quad*16);
            ah[0] = *(const bf16x8*)&sm[bc + XH_OFF + roA];
            al[0] = *(const bf16x8*)&sm[bc + XL_OFF + roA];
            ah[1] = *(const bf16x8*)&sm[bc + XH_OFF + roB];
            al[1] = *(const bf16x8*)&sm[bc + XL_OFF + roB];
        }
        // ---- 3-term MFMA per matrix
#define PROJ_MAT(WTH, WTL, ACC)                                               \
        {                                                                     \
            bf16x8 bh[4], bl[4];                                              \
            _Pragma("unroll")                                                 \
            for (int nt = 0; nt < 4; ++nt) {                                  \
                const unsigned bo = (unsigned)((nt*16 + l15)*80 + quad*16);   \
                bh[nt] = *(const bf16x8*)&sm[(WTH) + bo];                     \
                bl[nt] = *(const bf16x8*)&sm[(WTL) + bo];                     \
            }                                                                 \
            _Pragma("unroll")                                                 \
            for (int mt = 0; mt < 2; ++mt)                                    \
                _Pragma("unroll")                                             \
                for (int nt = 0; nt < 4; ++nt) {                              \
                    f32x4 a = ACC[mt][nt];                                    \
                    a = MFMA16(al[mt], bh[nt], a);                            \
                    a = MFMA16(ah[mt], bl[nt], a);                            \
                    a = MFMA16(ah[mt], bh[nt], a);                            \
                    ACC[mt][nt] = a;                                          \
                }                                                             \
        }
        PROJ_MAT(bc + W_OFF +     0u, bc + W_OFF +  5120u, qac)
        PROJ_MAT(bc + W_OFF + 10240u, bc + W_OFF + 15360u, kac)
        PROJ_MAT(bc + W_OFF + 20480u, bc + W_OFF + 25600u, vac)
        __syncthreads();   // chunk cc consumed; chunk cc+1 staged
    }

    // ====== Phase 1 epilogue: k -> khi/klo, v -> vT, q -> A-frags ==========
    constexpr float SCALE = 19.595917942265423f;   // sqrt(384) folded into q
    // C/D layout: row = quad*4 + reg (within 16-tile), col = l15.
    #pragma unroll
    for (int mt = 0; mt < 2; ++mt) {
        const int r0m = mt ? rB : rA;
        #pragma unroll
        for (int nt = 0; nt < 4; ++nt) {
            const f32x4 kv = kac[mt][nt];
            const f32x4 vv = vac[mt][nt];
            #pragma unroll
            for (int r = 0; r < 4; ++r) {
                const int row = r0m + quad*4 + r;
                const int h   = nt*16 + l15;
                *(unsigned short*)&sm[SM_KHI + (unsigned)(row*144 + h*2)] = bhi(kv[r]);
                *(unsigned short*)&sm[SM_KLO + (unsigned)(row*144 + h*2)] = blo(kv[r]);
                *(unsigned short*)&sm[SM_VT  + (unsigned)(h*528 + row*2)] = brne(vv[r]);
            }
        }
    }

    bf16x8 qAh[2][2], qAl[2][2];
    const int slot = w & 3;
    // two shifts through 4 q-transpose slots (aliased over staging region)
#define Q_XPOSE()                                                             \
    {                                                                         \
        const unsigned qb = SM_QS(slot);                                      \
        _Pragma("unroll")                                                     \
        for (int mt = 0; mt < 2; ++mt)                                        \
            _Pragma("unroll")                                                 \
            for (int nt = 0; nt < 4; ++nt) {                                  \
                const f32x4 qv = qac[mt][nt];                                 \
                _Pragma("unroll")                                             \
                for (int r = 0; r < 4; ++r) {                                 \
                    const float qs = qv[r] * SCALE;                           \
                    const int rl = mt*16 + quad*4 + r;                        \
                    const int h  = nt*16 + l15;                               \
                    *(unsigned short*)&sm[qb +         (unsigned)(rl*144 + h*2)] = bhi(qs); \
                    *(unsigned short*)&sm[qb + 4608u + (unsigned)(rl*144 + h*2)] = blo(qs); \
                }                                                             \
            }                                                                 \
        _Pragma("unroll")                                                     \
        for (int mt = 0; mt < 2; ++mt)                                        \
            _Pragma("unroll")                                                 \
            for (int ks = 0; ks < 2; ++ks) {                                  \
                const unsigned qo = (unsigned)((mt*16 + l15)*144 + ks*64 + quad*16); \
                qAh[mt][ks] = *(const bf16x8*)&sm[qb + qo];                   \
                qAl[mt][ks] = *(const bf16x8*)&sm[qb + 4608u + qo];           \
            }                                                                 \
    }
    if (w < 4) Q_XPOSE();
    __syncthreads();            // khi/klo/vT visible; slots free for waves 4..7
    if (w >= 4) Q_XPOSE();
    __syncthreads();            // q-slot area free -> becomes P slots

    // ================= Phase 2: flash attention, wave-local ================
    // Tile pairing (w, 15-w): iters = (w>>2)+1 + ((15-w)>>2)+1 == 5 for all w.
    f32x4 oac[2][4];
    float m_[2][4], l_[2][4];
    #pragma unroll
    for (int mt = 0; mt < 2; ++mt) {
        #pragma unroll
        for (int nt = 0; nt < 4; ++nt) { f32x4 z = {0.f,0.f,0.f,0.f}; oac[mt][nt] = z; }
        #pragma unroll
        for (int r = 0; r < 4; ++r) { m_[mt][r] = -1e30f; l_[mt][r] = 0.f; }
    }
    const unsigned pb = SM_PS(w);

    #pragma unroll
    for (int tile = 0; tile < 2; ++tile) {
        const int r0    = tile ? rB : rA;
        const int kbmax = tile ? ((15 - w) >> 2) : (w >> 2);
        #pragma unroll 1
        for (int kb = 0; kb <= kbmax; ++kb) {
            // ---- S = q k^T (3-term split), 16 rows x 64 keys
            bf16x8 kbh[4][2], kbl[4][2];
            #pragma unroll
            for (int nt = 0; nt < 4; ++nt)
                #pragma unroll
                for (int ks = 0; ks < 2; ++ks) {
                    const unsigned ko = (unsigned)((kb*64 + nt*16 + l15)*144 + ks*64 + quad*16);
                    kbh[nt][ks] = *(const bf16x8*)&sm[SM_KHI + ko];
                    kbl[nt][ks] = *(const bf16x8*)&sm[SM_KLO + ko];
                }
            f32x4 sac[4];
            #pragma unroll
            for (int nt = 0; nt < 4; ++nt) {
                f32x4 a = {0.f,0.f,0.f,0.f};
                #pragma unroll
                for (int ks = 0; ks < 2; ++ks) {
                    a = MFMA16(qAl[tile][ks], kbh[nt][ks], a);
                    a = MFMA16(qAh[tile][ks], kbl[nt][ks], a);
                    a = MFMA16(qAh[tile][ks], kbh[nt][ks], a);
                }
                sac[nt] = a;
            }
            // ---- causal mask on diagonal block (last kb always holds diag)
            if (kb == kbmax) {
                #pragma unroll
                for (int nt = 0; nt < 4; ++nt)
                    #pragma unroll
                    for (int r = 0; r < 4; ++r) {
                        const int rg = r0 + quad*4 + r;
                        const int kl = kb*64 + nt*16 + l15;
                        if (kl > rg) sac[nt][r] = -1e30f;
                    }
            }
            // ---- online softmax (row stats per (quad,reg); cols in lanes)
            #pragma unroll
            for (int r = 0; r < 4; ++r) {
                float v = fmaxf(fmaxf(sac[0][r], sac[1][r]), fmaxf(sac[2][r], sac[3][r]));
                v = fmaxf(v, __shfl_xor(v, 1)); v = fmaxf(v, __shfl_xor(v, 2));
                v = fmaxf(v, __shfl_xor(v, 4)); v = fmaxf(v, __shfl_xor(v, 8));
                const float mnew  = fmaxf(m_[tile][r], v);
                const float alpha = __expf(m_[tile][r] - mnew);
                m_[tile][r] = mnew;
                float rs = 0.f;
                #pragma unroll
                for (int nt = 0; nt < 4; ++nt) {
                    const float p = __expf(sac[nt][r] - mnew);
                    sac[nt][r] = p;
                    rs += p;
                }
                rs += __shfl_xor(rs, 1); rs += __shfl_xor(rs, 2);
                rs += __shfl_xor(rs, 4); rs += __shfl_xor(rs, 8);
                l_[tile][r] = l_[tile][r] * alpha + rs;
                #pragma unroll
                for (int nt = 0; nt < 4; ++nt) oac[tile][nt][r] *= alpha;
                // P -> bf16 in wave's P slot [16 rows][72 keys]
                const int rl = quad*4 + r;
                #pragma unroll
                for (int nt = 0; nt < 4; ++nt)
                    *(unsigned short*)&sm[pb + (unsigned)(rl*144 + (nt*16 + l15)*2)] =
                        brne(sac[nt][r]);
            }
            // ---- O += P V  (P via A-frags from wave slot; V from vT)
            bf16x8 pA[2], vB[4][2];
            #pragma unroll
            for (int ks = 0; ks < 2; ++ks)
                pA[ks] = *(const bf16x8*)&sm[pb + (unsigned)(l15*144 + ks*64 + quad*16)];
            #pragma unroll
            for (int nt = 0; nt < 4; ++nt)
                #pragma unroll
                for (int ks = 0; ks < 2; ++ks)
                    vB[nt][ks] = *(const bf16x8*)&sm[SM_VT + (unsigned)((nt*16 + l15)*528 + kb*128 + ks*64 + quad*16)];
            #pragma unroll
            for (int nt = 0; nt < 4; ++nt) {
                f32x4 a = oac[tile][nt];
                a = MFMA16(pA[0], vB[nt][0], a);
                a = MFMA16(pA[1], vB[nt][1], a);
                oac[tile][nt] = a;
            }
        }
    }

    // ================= Epilogue: normalize + store =========================
    float* ob = out + (size_t)b * (T_ * H_);
    #pragma unroll
    for (int mt = 0; mt < 2; ++mt) {
        const int r0m = mt ? rB : rA;
        float inv[4];
        #pragma unroll
        for (int r = 0; r < 4; ++r) inv[r] = 1.0f / l_[mt][r];
        #pragma unroll
        for (int nt = 0; nt < 4; ++nt)
            #pragma unroll
            for (int r = 0; r < 4; ++r) {
                const int row = r0m + quad*4 + r;
                const int h   = nt*16 + l15;
                ob[row*64 + h] = oac[mt][nt][r] * inv[r];
            }
    }
}

extern "C" void kernel_launch(void* const* d_in, const int* in_sizes, int n_in,
                              void* d_out, int out_size, void* d_ws, size_t ws_size,
                              hipStream_t stream)
{
    const float* x  = (const float*)d_in[0];
    const float* Wq = (const float*)d_in[1];
    const float* Wk = (const float*)d_in[2];
    const float* Wv = (const float*)d_in[3];
    // Pre-pack W (hi/lo bf16, staged-transposed) into workspace: 12*32768 = 384KB.
    wprep<<<dim3(36), dim3(256), 0, stream>>>(Wq, Wk, Wv, (unsigned char*)d_ws);
    head_mfma<<<dim3(B_), dim3(512), 0, stream>>>(x, (const unsigned char*)d_ws,
                                                  (float*)d_out);
}

// Round 5
// 328.327 us; speedup vs baseline: 1.0822x; 1.0822x over previous
//
#include <hip/hip_runtime.h>
#include <math.h>

// B=512, T=256, C=384, H=64. One block = one batch, 512 thr = 8 waves (2/SIMD).
// R8 = R6 structure + W staged via __builtin_amdgcn_global_load_lds (16B,
// async, zero registers, zero pack VALU). R6 lesson: W load->reg->LDS at loop
// top exposes vmem latency. R7 lesson: holding W in regs across MFMA spills
// (WRITE_SIZE 33->112MB, scratch write-back). global_load_lds removes the
// round-trip entirely; loads drain at the end-of-iter barrier, covered by the
// MFMA region. x keeps the proven one-iter-ahead reg prefetch (no spill @92).
// Numerics unchanged: 3-term bf16 hi/lo split for x,W,q,k; single bf16 P,V.
#define B_ 512
#define T_ 256
#define C_ 384
#define H_ 64

typedef __attribute__((ext_vector_type(8))) short bf16x8;
typedef __attribute__((ext_vector_type(4))) float f32x4;

#define MFMA16(a, b, c) __builtin_amdgcn_mfma_f32_16x16x32_bf16((a), (b), (c), 0, 0, 0)

// ---- LDS map (bytes), total 147456 <= 163840.
// Phase 1: two staging buffers buf[i] @ i*73728, each:
//   XH @+0 (xh[256][40] bf16, 80B rows), XL @+20480,
//   W  @+40960 (32768B: WQH,WQL,WKH,WKL,WVH,WVL @5120 each + 2048 pad).
// Phase 2 (aliased over the buffers, live only after phase 1):
//   KHI@0 khi[256][72], KLO@36864, VT@73728 vT[64][264],
//   QS(s)=107520+s*9216 (4 slots, two shifts), PS(w)=107520+w*2304.
#define BUFSZ    73728u
#define XH_OFF   0u
#define XL_OFF   20480u
#define W_OFF    40960u
#define SM_KHI   0u
#define SM_KLO   36864u
#define SM_VT    73728u
#define SM_QS(s) (107520u + (unsigned)(s)*9216u)
#define SM_PS(w) (107520u + (unsigned)(w)*2304u)
#define SM_BYTES 147456u
#define WCHUNK   32768u   // ws bytes per K-chunk (30720 live + pad)

static __device__ __forceinline__ unsigned short bhi(float x) {
    return (unsigned short)(__float_as_uint(x) >> 16);            // truncate
}
static __device__ __forceinline__ unsigned short blo(float x) {
    float h = __uint_as_float((__float_as_uint(x) >> 16) << 16);
    return (unsigned short)(__float_as_uint(x - h) >> 16);        // residual
}
static __device__ __forceinline__ unsigned short brne(float x) { // round-NE
    unsigned u = __float_as_uint(x);
    return (unsigned short)((u + 0x7FFFu + ((u >> 16) & 1u)) >> 16);
}
static __device__ __forceinline__ unsigned pk_hi(float a, float b) {
    return (unsigned)bhi(a) | ((unsigned)bhi(b) << 16);
}
static __device__ __forceinline__ unsigned pk_lo(float a, float b) {
    return (unsigned)blo(a) | ((unsigned)blo(b) << 16);
}

// ---- Pre-kernel: pack W -> ws in staged-transposed layout, once for all blocks.
// ws[cc*32768 + m*10240 + part*5120 + h*80 + c'*2] = {bhi,blo}(W_m[cc*32+c'][h])
__global__ __launch_bounds__(256)
void wprep(const float* __restrict__ Wq, const float* __restrict__ Wk,
           const float* __restrict__ Wv, unsigned char* __restrict__ ws)
{
    const int cc = blockIdx.x / 3, m = blockIdx.x % 3;
    const float* W = (m == 0) ? Wq : (m == 1) ? Wk : Wv;
    const int tid = threadIdx.x;           // 256 threads
    const int c   = tid >> 3;              // 0..31 (c within chunk)
    const int h0  = (tid & 7) * 8;         // 8 h per thread
    const float* src = W + (size_t)(cc * 32 + c) * H_ + h0;
    unsigned char* dst = ws + (size_t)cc * WCHUNK + (size_t)m * 10240u;
    #pragma unroll
    for (int j = 0; j < 8; ++j) {
        const float v = src[j];
        *(unsigned short*)(dst +         (unsigned)((h0 + j) * 80 + c * 2)) = bhi(v);
        *(unsigned short*)(dst + 5120u + (unsigned)((h0 + j) * 80 + c * 2)) = blo(v);
    }
}

__global__ __launch_bounds__(512, 2)
void head_mfma(const float* __restrict__ x,
               const unsigned char* __restrict__ wpack,
               float* __restrict__ out)
{
    __shared__ __align__(16) unsigned char sm[SM_BYTES];

    const int tid  = threadIdx.x;
    const int b    = blockIdx.x;
    const int w    = tid >> 6;        // wave 0..7
    const int lane = tid & 63;
    const int l15  = lane & 15;
    const int quad = lane >> 4;
    const int rA   = w * 16;          // tile A rows [rA, rA+16)
    const int rB   = 240 - w * 16;    // tile B rows [rB, rB+16)

    // ================= Phase 1: q,k,v projections via MFMA =================
    f32x4 qac[2][4], kac[2][4], vac[2][4];
    #pragma unroll
    for (int mt = 0; mt < 2; ++mt)
        #pragma unroll
        for (int nt = 0; nt < 4; ++nt) {
            f32x4 z = {0.f, 0.f, 0.f, 0.f};
            qac[mt][nt] = z; kac[mt][nt] = z; vac[mt][nt] = z;
        }

    const int xrowi = tid >> 1;           // staged x row 0..255
    const int xhalf = tid & 1;            // which 16-float half of the chunk
    const float* xrow = x + ((size_t)b * T_ + xrowi) * C_ + xhalf * 16;

    float4 xb[4];

#define X_PACK(BUF)                                                           \
    {                                                                         \
        _Pragma("unroll")                                                     \
        for (int j = 0; j < 4; ++j) {                                         \
            uint2 hh, ll;                                                     \
            hh.x = pk_hi(xb[j].x, xb[j].y); hh.y = pk_hi(xb[j].z, xb[j].w);   \
            ll.x = pk_lo(xb[j].x, xb[j].y); ll.y = pk_lo(xb[j].z, xb[j].w);   \
            *(uint2*)&sm[(BUF) + XH_OFF + (unsigned)(xrowi*80 + xhalf*32 + j*8)] = hh; \
            *(uint2*)&sm[(BUF) + XL_OFF + (unsigned)(xrowi*80 + xhalf*32 + j*8)] = ll; \
        }                                                                     \
    }
#define X_FETCH(CC)                                                           \
    {                                                                         \
        const float4* xp = (const float4*)(xrow + (CC) * 32);                 \
        _Pragma("unroll")                                                     \
        for (int j = 0; j < 4; ++j) xb[j] = xp[j];                            \
    }
// Async W staging: per-wave uniform LDS base + lane*16, linear layout.
#define W_LDS(CC, BUF)                                                        \
    {                                                                         \
        const unsigned char* gw = wpack + (size_t)(CC) * WCHUNK;              \
        _Pragma("unroll")                                                     \
        for (int j = 0; j < 4; ++j)                                           \
            __builtin_amdgcn_global_load_lds(                                 \
                (const __attribute__((address_space(1))) void*)               \
                    (gw + (unsigned)(j*512 + tid) * 16u),                     \
                (__attribute__((address_space(3))) void*)                     \
                    &sm[(BUF) + W_OFF + (unsigned)(j*512 + tid) * 16u],       \
                16, 0, 0);                                                    \
    }

    // ---- prologue: W chunk0 async -> buf0; x chunk0 pack -> buf0; x chunk1 regs
    W_LDS(0, 0u)
    X_FETCH(0)
    X_PACK(0u)
    X_FETCH(1)
    __syncthreads();   // drains W chunk0 + x chunk1 loads

    #pragma unroll 1
    for (int cc = 0; cc < 12; ++cc) {
        const unsigned bc = (unsigned)(cc & 1) * BUFSZ;   // compute buffer
        // ---- stage chunk cc+1 into spare buffer: x from regs (no wait),
        //      W async direct-to-LDS (drains at end barrier, under MFMAs)
        if (cc < 11) {
            const unsigned bn = BUFSZ - bc;
            X_PACK(bn)
            W_LDS(cc + 1, bn)
            if (cc < 10) X_FETCH(cc + 2)   // overlaps MFMAs below
        }

        // ---- A fragments for the wave's two 16-row tiles, hi & lo
        bf16x8 ah[2], al[2];
        {
            const unsigned roA = (unsigned)((rA + l15)*80 + quad*16);
            const unsigned roB = (unsigned)((rB + l15)*80 + quad*16);
            ah[0] = *(const bf16x8*)&sm[bc + XH_OFF + roA];
            al[0] = *(const bf16x8*)&sm[bc + XL_OFF + roA];
            ah[1] = *(const bf16x8*)&sm[bc + XH_OFF + roB];
            al[1] = *(const bf16x8*)&sm[bc + XL_OFF + roB];
        }
        // ---- 3-term MFMA per matrix
#define PROJ_MAT(WTH, WTL, ACC)                                               \
        {                                                                     \
            bf16x8 bh[4], bl[4];                                              \
            _Pragma("unroll")                                                 \
            for (int nt = 0; nt < 4; ++nt) {                                  \
                const unsigned bo = (unsigned)((nt*16 + l15)*80 + quad*16);   \
                bh[nt] = *(const bf16x8*)&sm[(WTH) + bo];                     \
                bl[nt] = *(const bf16x8*)&sm[(WTL) + bo];                     \
            }                                                                 \
            _Pragma("unroll")                                                 \
            for (int mt = 0; mt < 2; ++mt)                                    \
                _Pragma("unroll")                                             \
                for (int nt = 0; nt < 4; ++nt) {                              \
                    f32x4 a = ACC[mt][nt];                                    \
                    a = MFMA16(al[mt], bh[nt], a);                            \
                    a = MFMA16(ah[mt], bl[nt], a);                            \
                    a = MFMA16(ah[mt], bh[nt], a);                            \
                    ACC[mt][nt] = a;                                          \
                }                                                             \
        }
        PROJ_MAT(bc + W_OFF +     0u, bc + W_OFF +  5120u, qac)
        PROJ_MAT(bc + W_OFF + 10240u, bc + W_OFF + 15360u, kac)
        PROJ_MAT(bc + W_OFF + 20480u, bc + W_OFF + 25600u, vac)
        __syncthreads();   // chunk cc consumed; chunk cc+1 staged
    }

    // ====== Phase 1 epilogue: k -> khi/klo, v -> vT, q -> A-frags ==========
    constexpr float SCALE = 19.595917942265423f;   // sqrt(384) folded into q
    // C/D layout: row = quad*4 + reg (within 16-tile), col = l15.
    #pragma unroll
    for (int mt = 0; mt < 2; ++mt) {
        const int r0m = mt ? rB : rA;
        #pragma unroll
        for (int nt = 0; nt < 4; ++nt) {
            const f32x4 kv = kac[mt][nt];
            const f32x4 vv = vac[mt][nt];
            #pragma unroll
            for (int r = 0; r < 4; ++r) {
                const int row = r0m + quad*4 + r;
                const int h   = nt*16 + l15;
                *(unsigned short*)&sm[SM_KHI + (unsigned)(row*144 + h*2)] = bhi(kv[r]);
                *(unsigned short*)&sm[SM_KLO + (unsigned)(row*144 + h*2)] = blo(kv[r]);
                *(unsigned short*)&sm[SM_VT  + (unsigned)(h*528 + row*2)] = brne(vv[r]);
            }
        }
    }

    bf16x8 qAh[2][2], qAl[2][2];
    const int slot = w & 3;
    // two shifts through 4 q-transpose slots (aliased over staging region)
#define Q_XPOSE()                                                             \
    {                                                                         \
        const unsigned qb = SM_QS(slot);                                      \
        _Pragma("unroll")                                                     \
        for (int mt = 0; mt < 2; ++mt)                                        \
            _Pragma("unroll")                                                 \
            for (int nt = 0; nt < 4; ++nt) {                                  \
                const f32x4 qv = qac[mt][nt];                                 \
                _Pragma("unroll")                                             \
                for (int r = 0; r < 4; ++r) {                                 \
                    const float qs = qv[r] * SCALE;                           \
                    const int rl = mt*16 + quad*4 + r;                        \
                    const int h  = nt*16 + l15;                               \
                    *(unsigned short*)&sm[qb +         (unsigned)(rl*144 + h*2)] = bhi(qs); \
                    *(unsigned short*)&sm[qb + 4608u + (unsigned)(rl*144 + h*2)] = blo(qs); \
                }                                                             \
            }                                                                 \
        _Pragma("unroll")                                                     \
        for (int mt = 0; mt < 2; ++mt)                                        \
            _Pragma("unroll")                                                 \
            for (int ks = 0; ks < 2; ++ks) {                                  \
                const unsigned qo = (unsigned)((mt*16 + l15)*144 + ks*64 + quad*16); \
                qAh[mt][ks] = *(const bf16x8*)&sm[qb + qo];                   \
                qAl[mt][ks] = *(const bf16x8*)&sm[qb + 4608u + qo];           \
            }                                                                 \
    }
    if (w < 4) Q_XPOSE();
    __syncthreads();            // khi/klo/vT visible; slots free for waves 4..7
    if (w >= 4) Q_XPOSE();
    __syncthreads();            // q-slot area free -> becomes P slots

    // ================= Phase 2: flash attention, wave-local ================
    // Tile pairing (w, 15-w): iters = (w>>2)+1 + ((15-w)>>2)+1 == 5 for all w.
    f32x4 oac[2][4];
    float m_[2][4], l_[2][4];
    #pragma unroll
    for (int mt = 0; mt < 2; ++mt) {
        #pragma unroll
        for (int nt = 0; nt < 4; ++nt) { f32x4 z = {0.f,0.f,0.f,0.f}; oac[mt][nt] = z; }
        #pragma unroll
        for (int r = 0; r < 4; ++r) { m_[mt][r] = -1e30f; l_[mt][r] = 0.f; }
    }
    const unsigned pb = SM_PS(w);

    #pragma unroll
    for (int tile = 0; tile < 2; ++tile) {
        const int r0    = tile ? rB : rA;
        const int kbmax = tile ? ((15 - w) >> 2) : (w >> 2);
        #pragma unroll 1
        for (int kb = 0; kb <= kbmax; ++kb) {
            // ---- S = q k^T (3-term split), 16 rows x 64 keys
            bf16x8 kbh[4][2], kbl[4][2];
            #pragma unroll
            for (int nt = 0; nt < 4; ++nt)
                #pragma unroll
                for (int ks = 0; ks < 2; ++ks) {
                    const unsigned ko = (unsigned)((kb*64 + nt*16 + l15)*144 + ks*64 + quad*16);
                    kbh[nt][ks] = *(const bf16x8*)&sm[SM_KHI + ko];
                    kbl[nt][ks] = *(const bf16x8*)&sm[SM_KLO + ko];
                }
            f32x4 sac[4];
            #pragma unroll
            for (int nt = 0; nt < 4; ++nt) {
                f32x4 a = {0.f,0.f,0.f,0.f};
                #pragma unroll
                for (int ks = 0; ks < 2; ++ks) {
                    a = MFMA16(qAl[tile][ks], kbh[nt][ks], a);
                    a = MFMA16(qAh[tile][ks], kbl[nt][ks], a);
                    a = MFMA16(qAh[tile][ks], kbh[nt][ks], a);
                }
                sac[nt] = a;
            }
            // ---- causal mask on diagonal block (last kb always holds diag)
            if (kb == kbmax) {
                #pragma unroll
                for (int nt = 0; nt < 4; ++nt)
                    #pragma unroll
                    for (int r = 0; r < 4; ++r) {
                        const int rg = r0 + quad*4 + r;
                        const int kl = kb*64 + nt*16 + l15;
                        if (kl > rg) sac[nt][r] = -1e30f;
                    }
            }
            // ---- online softmax (row stats per (quad,reg); cols in lanes)
            #pragma unroll
            for (int r = 0; r < 4; ++r) {
                float v = fmaxf(fmaxf(sac[0][r], sac[1][r]), fmaxf(sac[2][r], sac[3][r]));
                v = fmaxf(v, __shfl_xor(v, 1)); v = fmaxf(v, __shfl_xor(v, 2));
                v = fmaxf(v, __shfl_xor(v, 4)); v = fmaxf(v, __shfl_xor(v, 8));
                const float mnew  = fmaxf(m_[tile][r], v);
                const float alpha = __expf(m_[tile][r] - mnew);
                m_[tile][r] = mnew;
                float rs = 0.f;
                #pragma unroll
                for (int nt = 0; nt < 4; ++nt) {
                    const float p = __expf(sac[nt][r] - mnew);
                    sac[nt][r] = p;
                    rs += p;
                }
                rs += __shfl_xor(rs, 1); rs += __shfl_xor(rs, 2);
                rs += __shfl_xor(rs, 4); rs += __shfl_xor(rs, 8);
                l_[tile][r] = l_[tile][r] * alpha + rs;
                #pragma unroll
                for (int nt = 0; nt < 4; ++nt) oac[tile][nt][r] *= alpha;
                // P -> bf16 in wave's P slot [16 rows][72 keys]
                const int rl = quad*4 + r;
                #pragma unroll
                for (int nt = 0; nt < 4; ++nt)
                    *(unsigned short*)&sm[pb + (unsigned)(rl*144 + (nt*16 + l15)*2)] =
                        brne(sac[nt][r]);
            }
            // ---- O += P V  (P via A-frags from wave slot; V from vT)
            bf16x8 pA[2], vB[4][2];
            #pragma unroll
            for (int ks = 0; ks < 2; ++ks)
                pA[ks] = *(const bf16x8*)&sm[pb + (unsigned)(l15*144 + ks*64 + quad*16)];
            #pragma unroll
            for (int nt = 0; nt < 4; ++nt)
                #pragma unroll
                for (int ks = 0; ks < 2; ++ks)
                    vB[nt][ks] = *(const bf16x8*)&sm[SM_VT + (unsigned)((nt*16 + l15)*528 + kb*128 + ks*64 + quad*16)];
            #pragma unroll
            for (int nt = 0; nt < 4; ++nt) {
                f32x4 a = oac[tile][nt];
                a = MFMA16(pA[0], vB[nt][0], a);
                a = MFMA16(pA[1], vB[nt][1], a);
                oac[tile][nt] = a;
            }
        }
    }

    // ================= Epilogue: normalize + store =========================
    float* ob = out + (size_t)b * (T_ * H_);
    #pragma unroll
    for (int mt = 0; mt < 2; ++mt) {
        const int r0m = mt ? rB : rA;
        float inv[4];
        #pragma unroll
        for (int r = 0; r < 4; ++r) inv[r] = 1.0f / l_[mt][r];
        #pragma unroll
        for (int nt = 0; nt < 4; ++nt)
            #pragma unroll
            for (int r = 0; r < 4; ++r) {
                const int row = r0m + quad*4 + r;
                const int h   = nt*16 + l15;
                ob[row*64 + h] = oac[mt][nt][r] * inv[r];
            }
    }
}

extern "C" void kernel_launch(void* const* d_in, const int* in_sizes, int n_in,
                              void* d_out, int out_size, void* d_ws, size_t ws_size,
                              hipStream_t stream)
{
    const float* x  = (const float*)d_in[0];
    const float* Wq = (const float*)d_in[1];
    const float* Wk = (const float*)d_in[2];
    const float* Wv = (const float*)d_in[3];
    // Pre-pack W (hi/lo bf16, staged-transposed) into workspace: 12*32768 = 384KB.
    wprep<<<dim3(36), dim3(256), 0, stream>>>(Wq, Wk, Wv, (unsigned char*)d_ws);
    head_mfma<<<dim3(B_), dim3(512), 0, stream>>>(x, (const unsigned char*)d_ws,
                                                  (float*)d_out);
}